// Round 1
// 318.742 us; speedup vs baseline: 1.2121x; 1.2121x over previous
//
#include <hip/hip_runtime.h>
#include <math.h>

#define B_ 16
#define H_ 224
#define W_ 224
#define HP_ 226
#define WP_ 226
#define CIN_ 3
#define COUT_ 64
#define NPIX_ (B_ * H_ * W_)      /* 802816 */
#define NPAD_ (B_ * HP_ * WP_)    /* 817216 */
#define NBLK_ (NPIX_ / 256)       /* 3136 */
#define MAXNORM_ 0.999f
#define MINN_ 1e-7f
#define TCL_ (1.0f - 1e-5f)
#define LCLAMP_ 3.8002012f        /* atanh(0.999) */
#define BN_EPS_ 1e-5f
#define NF_ ((float)NPIX_)
/* Padded LDS row width (floats): 64 ch + 4 pad. Row stride 272 B stays 16 B
   aligned for ds_*_b128, and (68*p)%32 = (4p)%32 spreads rows across banks.
   Column reads (stride-68 floats, lane-offset l) hit bank (4p+l)%32 ->
   exactly 2 lanes/bank = free (m136). */
#define PADW_ 68

typedef float v4f __attribute__((ext_vector_type(4)));

// 64 accumulators as 16 NAMED vector members. Never indexed with a variable:
// all access is macro-expanded constant member names -> first-class SSA values,
// immune to the SROA-before-unroll alloca trap that left R1/R2 at 48 VGPRs with
// 250+ MB of scratch spill traffic (WRITE_SIZE 2.5x ideal, VGPR_Count frozen).
struct Acc {
  v4f v0, v1, v2, v3, v4, v5, v6, v7, v8, v9, v10, v11, v12, v13, v14, v15;
};

#define EACH16(X) X(0) X(1) X(2) X(3) X(4) X(5) X(6) X(7) \
                  X(8) X(9) X(10) X(11) X(12) X(13) X(14) X(15)

// ---------------------------------------------------------------------------
// K0: x (NCHW f32) -> u0p (padded NHWC4): u0 = logmap0(projx(x)) per pixel,
// zero halo ring (SAME padding happens in tangent space). ws is re-poisoned
// every launch, so the halo must be rewritten every call.
// ---------------------------------------------------------------------------
__global__ void k0_transform(const float* __restrict__ x, float4* __restrict__ u0p) {
  int idx = blockIdx.x * 256 + threadIdx.x;
  if (idx >= NPAD_) return;
  int b = idx / (HP_ * WP_);
  int r = idx % (HP_ * WP_);
  int yp = r / WP_, xp = r % WP_;
  float4 o = make_float4(0.f, 0.f, 0.f, 0.f);
  if (yp >= 1 && yp <= H_ && xp >= 1 && xp <= W_) {
    const float* xb = x + (size_t)b * (CIN_ * H_ * W_) + (size_t)(yp - 1) * W_ + (xp - 1);
    float v0 = xb[0];
    float v1 = xb[H_ * W_];
    float v2 = xb[2 * H_ * W_];
    // projx
    float n = sqrtf(fmaf(v0, v0, fmaf(v1, v1, v2 * v2)));
    float ncl = fmaxf(n, MINN_);
    float s = fminf(1.0f, MAXNORM_ / ncl);
    float p0 = v0 * s, p1 = v1 * s, p2 = v2 * s;
    // logmap0
    float np_ = fmaxf(sqrtf(fmaf(p0, p0, fmaf(p1, p1, p2 * p2))), MINN_);
    float t = fminf(np_, TCL_);
    float f = atanhf(t) / np_;
    o.x = p0 * f; o.y = p1 * f; o.z = p2 * f;
  }
  u0p[idx] = o;
}

// ---------------------------------------------------------------------------
// Shared conv: one thread = one output pixel, all 64 output channels live in
// 16 named v4f registers. Weight addresses are wave-uniform -> scalar loads.
// Fused logmap0(projx(expmap0(t))) == t * min(1, L/||t||).
// ---------------------------------------------------------------------------
__device__ __forceinline__ void conv_clamp(const float4* __restrict__ u0p,
                                           const float* __restrict__ wgt,
                                           const float* __restrict__ bias,
                                           int pix, Acc& a) {
  int b = pix / (H_ * W_);
  int r = pix % (H_ * W_);
  int y = r / W_, x = r % W_;
  const float4* base = u0p + ((size_t)b * HP_ + y) * WP_ + x;
  const v4f* b4 = (const v4f*)bias;
#define INIT(i) a.v##i = b4[i];
  EACH16(INIT)
#undef INIT
#define FMA_X(i) a.v##i += in.x * wp[i];
#define FMA_Y(i) a.v##i += in.y * wp[16 + i];
#define FMA_Z(i) a.v##i += in.z * wp[32 + i];
#define TAP(t) { float4 in = base[((t) / 3) * WP_ + ((t) % 3)];              \
                 const v4f* wp = (const v4f*)(wgt + (t) * 3 * COUT_);        \
                 EACH16(FMA_X) EACH16(FMA_Y) EACH16(FMA_Z) }
  TAP(0) TAP(1) TAP(2) TAP(3) TAP(4) TAP(5) TAP(6) TAP(7) TAP(8)
#undef TAP
#undef FMA_X
#undef FMA_Y
#undef FMA_Z
  v4f s2 = (v4f)0.0f;
#define SQ(i) s2 += a.v##i * a.v##i;
  EACH16(SQ)
#undef SQ
  float n2 = s2.x + s2.y + s2.z + s2.w;
  float n = sqrtf(n2);
  float sc = (n > LCLAMP_) ? (LCLAMP_ / n) : 1.0f;
#define SCL(i) a.v##i *= sc;
  EACH16(SCL)
}

// ---------------------------------------------------------------------------
// K1: conv + clamp, then wave-private LDS transpose-reduce. Each wave stages
// its 64pix x 64ch f32 tile row-major (16 ds_write_b128/thread), then lane l
// walks COLUMN l (64 ds_read_b32, addr p*68+l -> 2 lanes/bank = conflict-free)
// accumulating sum and sumsq in one pass. Replaces the 2x fold64 butterfly
// (252 ds_swizzle + 252 VALU + ~230 live VGPRs) -> ~2.5x fewer LDS-pipe ops,
// no q[] array, no fold temps. Wave-private region: DS ops from one wave
// complete in order, so no __syncthreads before the column reads.
// ---------------------------------------------------------------------------
__global__ void __launch_bounds__(256, 2)
k1_stats(const float4* __restrict__ u0p, const float* __restrict__ wgt,
         const float* __restrict__ bias, float* __restrict__ partials) {
  int pix = blockIdx.x * 256 + threadIdx.x;
  Acc a;
  conv_clamp(u0p, wgt, bias, pix, a);

  __shared__ __align__(16) float stg[4 * 64 * PADW_];  // 69,632 B
  __shared__ float red[512];
  int lane = threadIdx.x & 63, wid = threadIdx.x >> 6;

  float* row = stg + (size_t)(wid * 64 + lane) * PADW_;
#define STG(i) *(v4f*)(row + 4 * (i)) = a.v##i;
  EACH16(STG)
#undef STG
  __builtin_amdgcn_wave_barrier();  // keep compiler from sinking writes past reads

  const float* col = stg + (size_t)wid * 64 * PADW_ + lane;
  float s0 = 0.f, s1 = 0.f, s2 = 0.f, s3 = 0.f;
  float q0 = 0.f, q1 = 0.f, q2 = 0.f, q3 = 0.f;
#pragma unroll
  for (int p = 0; p < 64; p += 4) {
    float a0 = col[(p + 0) * PADW_];
    float a1 = col[(p + 1) * PADW_];
    float a2 = col[(p + 2) * PADW_];
    float a3 = col[(p + 3) * PADW_];
    s0 += a0; q0 = fmaf(a0, a0, q0);
    s1 += a1; q1 = fmaf(a1, a1, q1);
    s2 += a2; q2 = fmaf(a2, a2, q2);
    s3 += a3; q3 = fmaf(a3, a3, q3);
  }
  float s_tot = (s0 + s1) + (s2 + s3);   // lane l == channel l wave-total
  float q_tot = (q0 + q1) + (q2 + q3);

  red[wid * 64 + lane] = s_tot;
  red[256 + wid * 64 + lane] = q_tot;
  __syncthreads();
  int tid = threadIdx.x;
  if (tid < 128) {
    int off = (tid < 64) ? 0 : (256 - 64);
    float tot = red[off + tid] + red[off + tid + 64] + red[off + tid + 128] + red[off + tid + 192];
    // partials[blk*128 + c] = sum_c ; partials[blk*128 + 64 + c] = sumsq_c
    partials[(size_t)blockIdx.x * 128 + tid] = tot;
  }
}

// ---------------------------------------------------------------------------
// K2: reduce 3136 x 128 partials -> mean[c], rstd*gamma[c]. One 1024-thread
// block, float4 chunked 32-way so ~8 loads are in flight per thread.
// ---------------------------------------------------------------------------
__global__ void k2_finalize(const float* __restrict__ partials, const float* __restrict__ gamma,
                            float* __restrict__ stats) {
  __shared__ float lds[32 * 128 + 128];
  int tid = threadIdx.x;  // 1024 threads
  int chunk = tid >> 5, qi = tid & 31;
  const float4* p4 = (const float4*)partials;
  float4 a = make_float4(0.f, 0.f, 0.f, 0.f);
#pragma unroll 7
  for (int i = chunk; i < NBLK_; i += 32) {
    float4 v = p4[(size_t)i * 32 + qi];
    a.x += v.x; a.y += v.y; a.z += v.z; a.w += v.w;
  }
  lds[chunk * 128 + qi * 4 + 0] = a.x;
  lds[chunk * 128 + qi * 4 + 1] = a.y;
  lds[chunk * 128 + qi * 4 + 2] = a.z;
  lds[chunk * 128 + qi * 4 + 3] = a.w;
  __syncthreads();
  if (tid < 128) {
    float tot = 0.f;
#pragma unroll
    for (int ch = 0; ch < 32; ch++) tot += lds[ch * 128 + tid];
    lds[32 * 128 + tid] = tot;
  }
  __syncthreads();
  if (tid < 64) {
    float mean = lds[32 * 128 + tid] / NF_;
    float msq  = lds[32 * 128 + 64 + tid] / NF_;
    float var = msq - mean * mean;            // jnp.var (ddof=0)
    float rstdg = gamma[tid] / sqrtf(var + BN_EPS_);
    stats[tid] = mean;
    stats[64 + tid] = rstdg;
  }
}

// ---------------------------------------------------------------------------
// K3: conv + clamp + BN affine + clamp + ReLU + real expmap0 (+projx), then
// wave-private LDS transpose so the wave's 16 KB output region is stored as
// 16 fully-coalesced 1 KB instructions (64 lanes x contiguous float4).
// The old direct store (16B/lane at 256B stride) caused 2.2x WRITE_SIZE
// amplification (456 MB HBM writes for a 205 MB output) and capped k3 at
// 3.4 TB/s of mostly-wasted write bandwidth.
// ---------------------------------------------------------------------------
__global__ void __launch_bounds__(256, 2)
k3_final(const float4* __restrict__ u0p, const float* __restrict__ wgt,
         const float* __restrict__ bias, const float* __restrict__ stats,
         const float* __restrict__ beta, float* __restrict__ out) {
  int pix = blockIdx.x * 256 + threadIdx.x;
  Acc a;
  conv_clamp(u0p, wgt, bias, pix, a);
  const v4f* mean4 = (const v4f*)stats;
  const v4f* rg4   = (const v4f*)(stats + 64);
  const v4f* beta4 = (const v4f*)beta;
  v4f s2 = (v4f)0.0f;
#define BN(i) { a.v##i = (a.v##i - mean4[i]) * rg4[i] + beta4[i]; s2 += a.v##i * a.v##i; }
  EACH16(BN)
#undef BN
  float nv2 = s2.x + s2.y + s2.z + s2.w;
  float nv = sqrtf(nv2);
  float sv = (nv > LCLAMP_) ? (LCLAMP_ / nv) : 1.0f;  // logmap0(expmap0(v)) fused
  // ReLU in tangent space
  v4f z2 = (v4f)0.0f;
#define RELU(i) { v4f r = a.v##i * sv;                                      \
                  r.x = fmaxf(r.x, 0.f); r.y = fmaxf(r.y, 0.f);             \
                  r.z = fmaxf(r.z, 0.f); r.w = fmaxf(r.w, 0.f);             \
                  a.v##i = r; z2 += r * r; }
  EACH16(RELU)
#undef RELU
  float nw2 = z2.x + z2.y + z2.z + z2.w;
  // final expmap0 + projx (the only real tanh)
  float nw = fmaxf(sqrtf(nw2), MINN_);
  float th = tanhf(nw);
  float se = th / nw;
  float clip = fminf(1.0f, MAXNORM_ / fmaxf(th, MINN_));
  float fs = se * clip;

  // ---- coalescing transpose: registers -> wave-private LDS tile -> global ----
  __shared__ __align__(16) float stg[4 * 64 * PADW_];  // 69,632 B -> 2 blk/CU
  int lane = threadIdx.x & 63, wid = threadIdx.x >> 6;
  float* row = stg + (size_t)(wid * 64 + lane) * PADW_;
#define STG(i) *(v4f*)(row + 4 * (i)) = a.v##i * fs;
  EACH16(STG)
#undef STG
  __builtin_amdgcn_wave_barrier();  // wave-private: DS in-order, no __syncthreads

  const float* wbuf = stg + (size_t)wid * 64 * PADW_;
  v4f* outw = (v4f*)out + ((size_t)blockIdx.x * 256 + wid * 64) * 16;
  int pr = lane >> 4, ci = lane & 15;
  const float* rbase = wbuf + pr * PADW_ + ci * 4;
#pragma unroll
  for (int j = 0; j < 16; j++) {
    // instr j: lanes cover out floats [j*256 .. j*256+255] of this wave's
    // 16 KB region -> one aligned contiguous 1 KB store per instruction.
    v4f v = *(const v4f*)(rbase + j * 4 * PADW_);
    __builtin_nontemporal_store(v, outw + j * 64 + lane);
  }
}

// ---------------------------------------------------------------------------
extern "C" void kernel_launch(void* const* d_in, const int* in_sizes, int n_in,
                              void* d_out, int out_size, void* d_ws, size_t ws_size,
                              hipStream_t stream) {
  const float* x     = (const float*)d_in[0];  // [16,3,224,224]
  const float* wgt   = (const float*)d_in[1];  // [3,3,3,64] HWIO
  const float* bias  = (const float*)d_in[2];  // [64]
  const float* gamma = (const float*)d_in[3];  // [64]
  const float* beta  = (const float*)d_in[4];  // [64]
  float* out = (float*)d_out;                  // [16,224,224,64]

  char* ws = (char*)d_ws;
  float4* u0p      = (float4*)ws;                                           // 13,075,456 B
  float*  partials = (float*)(ws + (size_t)NPAD_ * 16);                     //  1,605,632 B
  float*  stats    = (float*)(ws + (size_t)NPAD_ * 16 + (size_t)NBLK_ * 128 * 4); // 512 B

  hipLaunchKernelGGL(k0_transform, dim3((NPAD_ + 255) / 256), dim3(256), 0, stream, x, u0p);
  hipLaunchKernelGGL(k1_stats,     dim3(NBLK_),               dim3(256), 0, stream, u0p, wgt, bias, partials);
  hipLaunchKernelGGL(k2_finalize,  dim3(1),                   dim3(1024), 0, stream, partials, gamma, stats);
  hipLaunchKernelGGL(k3_final,     dim3(NBLK_),               dim3(256), 0, stream, u0p, wgt, bias, stats, beta, out);
}

// Round 2
// 307.917 us; speedup vs baseline: 1.2547x; 1.0352x over previous
//
#include <hip/hip_runtime.h>
#include <math.h>

#define B_ 16
#define H_ 224
#define W_ 224
#define HP_ 226
#define WP_ 226
#define CIN_ 3
#define COUT_ 64
#define NPIX_ (B_ * H_ * W_)      /* 802816 */
#define NPAD_ (B_ * HP_ * WP_)    /* 817216 */
#define NBLK_ (NPIX_ / 256)       /* 3136 */
#define MAXNORM_ 0.999f
#define MINN_ 1e-7f
#define TCL_ (1.0f - 1e-5f)
#define LCLAMP_ 3.8002012f        /* atanh(0.999) */
#define BN_EPS_ 1e-5f
#define NF_ ((float)NPIX_)
/* Half-tile LDS row stride (floats): 32 ch + 4 pad = 36 = 9 quads.
   9 is ODD -> b128 accesses spread across the 8 bank-groups evenly (the
   64-lane x 16B = 1KB access has a hard 8-cycle floor; odd quad stride keeps
   it at the floor). Column b32 reads: bank (4p + c) % 32 -> 2 lanes/bank =
   free (m136). Halving the tile from 64 to 32 channels cuts LDS/block from
   69,632 B (2 blk/CU) to 38,912 B -> 4 blk/CU: the R1 kernels were stuck at
   2 waves/SIMD, too few to hide tap-load + LDS latency. */
#define PADW2_ 36

typedef float v4f __attribute__((ext_vector_type(4)));

// 64 accumulators as 16 NAMED vector members. Never indexed with a variable:
// all access is macro-expanded constant member names -> first-class SSA values,
// immune to the SROA-before-unroll alloca trap that left R1/R2 at 48 VGPRs with
// 250+ MB of scratch spill traffic (WRITE_SIZE 2.5x ideal, VGPR_Count frozen).
struct Acc {
  v4f v0, v1, v2, v3, v4, v5, v6, v7, v8, v9, v10, v11, v12, v13, v14, v15;
};

#define EACH16(X) X(0) X(1) X(2) X(3) X(4) X(5) X(6) X(7) \
                  X(8) X(9) X(10) X(11) X(12) X(13) X(14) X(15)
#define EACH8LO(X) X(0) X(1) X(2) X(3) X(4) X(5) X(6) X(7)
#define EACH8HI(X) X(8) X(9) X(10) X(11) X(12) X(13) X(14) X(15)

// ---------------------------------------------------------------------------
// K0: x (NCHW f32) -> u0p (padded NHWC4): u0 = logmap0(projx(x)) per pixel,
// zero halo ring (SAME padding happens in tangent space). ws is re-poisoned
// every launch, so the halo must be rewritten every call.
// atanh via hardware log: atanh(t) = 0.5*log((1+t)/(1-t)) -- libm atanhf is
// a branchy ~40-instr call; v_log_f32 + fast div is ~8.
// ---------------------------------------------------------------------------
__global__ void k0_transform(const float* __restrict__ x, float4* __restrict__ u0p) {
  int idx = blockIdx.x * 256 + threadIdx.x;
  if (idx >= NPAD_) return;
  int b = idx / (HP_ * WP_);
  int r = idx % (HP_ * WP_);
  int yp = r / WP_, xp = r % WP_;
  float4 o = make_float4(0.f, 0.f, 0.f, 0.f);
  if (yp >= 1 && yp <= H_ && xp >= 1 && xp <= W_) {
    const float* xb = x + (size_t)b * (CIN_ * H_ * W_) + (size_t)(yp - 1) * W_ + (xp - 1);
    float v0 = xb[0];
    float v1 = xb[H_ * W_];
    float v2 = xb[2 * H_ * W_];
    // projx
    float n = sqrtf(fmaf(v0, v0, fmaf(v1, v1, v2 * v2)));
    float ncl = fmaxf(n, MINN_);
    float s = fminf(1.0f, MAXNORM_ / ncl);
    float p0 = v0 * s, p1 = v1 * s, p2 = v2 * s;
    // logmap0
    float np_ = fmaxf(sqrtf(fmaf(p0, p0, fmaf(p1, p1, p2 * p2))), MINN_);
    float t = fminf(np_, TCL_);
    float ath = 0.5f * __logf(__fdividef(1.0f + t, 1.0f - t));
    float f = __fdividef(ath, np_);
    o.x = p0 * f; o.y = p1 * f; o.z = p2 * f;
  }
  u0p[idx] = o;
}

// ---------------------------------------------------------------------------
// Shared conv: one thread = one output pixel, all 64 output channels live in
// 16 named v4f registers. Weight addresses are wave-uniform -> scalar loads.
// Fused logmap0(projx(expmap0(t))) == t * min(1, L/||t||).
// ---------------------------------------------------------------------------
__device__ __forceinline__ void conv_clamp(const float4* __restrict__ u0p,
                                           const float* __restrict__ wgt,
                                           const float* __restrict__ bias,
                                           int pix, Acc& a) {
  int b = pix / (H_ * W_);
  int r = pix % (H_ * W_);
  int y = r / W_, x = r % W_;
  const float4* base = u0p + ((size_t)b * HP_ + y) * WP_ + x;
  const v4f* b4 = (const v4f*)bias;
#define INIT(i) a.v##i = b4[i];
  EACH16(INIT)
#undef INIT
#define FMA_X(i) a.v##i += in.x * wp[i];
#define FMA_Y(i) a.v##i += in.y * wp[16 + i];
#define FMA_Z(i) a.v##i += in.z * wp[32 + i];
#define TAP(t) { float4 in = base[((t) / 3) * WP_ + ((t) % 3)];              \
                 const v4f* wp = (const v4f*)(wgt + (t) * 3 * COUT_);        \
                 EACH16(FMA_X) EACH16(FMA_Y) EACH16(FMA_Z) }
  TAP(0) TAP(1) TAP(2) TAP(3) TAP(4) TAP(5) TAP(6) TAP(7) TAP(8)
#undef TAP
#undef FMA_X
#undef FMA_Y
#undef FMA_Z
  v4f s2 = (v4f)0.0f;
#define SQ(i) s2 += a.v##i * a.v##i;
  EACH16(SQ)
#undef SQ
  float n2 = s2.x + s2.y + s2.z + s2.w;
  float n = sqrtf(n2);
  float sc = (n > LCLAMP_) ? (LCLAMP_ / n) : 1.0f;
#define SCL(i) a.v##i *= sc;
  EACH16(SCL)
}

// ---------------------------------------------------------------------------
// K1: conv + clamp, then wave-private LDS transpose-reduce in TWO 32-channel
// half-passes (half-size tile -> 4 blk/CU). Pass A stages ch 0-31 (v0..v7),
// lane l sums column (l&31) over pixel range (l>>5)*32..+31, sum+sumsq in one
// walk; shfl_xor(32) merges the pixel halves. Pass B repeats for ch 32-63.
// Wave-private region: DS ops from one wave complete in order, so only
// wave_barrier (compiler fences) between phases, no __syncthreads.
// ---------------------------------------------------------------------------
__global__ void __launch_bounds__(256, 4)
k1_stats(const float4* __restrict__ u0p, const float* __restrict__ wgt,
         const float* __restrict__ bias, float* __restrict__ partials) {
  int pix = blockIdx.x * 256 + threadIdx.x;
  Acc a;
  conv_clamp(u0p, wgt, bias, pix, a);

  __shared__ __align__(16) float stg[4 * 64 * PADW2_];  // 36,864 B
  __shared__ float red[512];                            //  2,048 B
  int lane = threadIdx.x & 63, wid = threadIdx.x >> 6;
  float* row = stg + (size_t)(wid * 64 + lane) * PADW2_;
  int c = lane & 31, half = lane >> 5;
  const float* col = stg + ((size_t)wid * 64 + half * 32) * PADW2_ + c;

  // ---- pass A: channels 0..31 ----
#define STGA(i) *(v4f*)(row + 4 * (i)) = a.v##i;
  EACH8LO(STGA)
#undef STGA
  __builtin_amdgcn_wave_barrier();
  float sA0 = 0.f, sA1 = 0.f, qA0 = 0.f, qA1 = 0.f;
#pragma unroll
  for (int p = 0; p < 32; p += 2) {
    float a0 = col[(p + 0) * PADW2_];
    float a1 = col[(p + 1) * PADW2_];
    sA0 += a0; qA0 = fmaf(a0, a0, qA0);
    sA1 += a1; qA1 = fmaf(a1, a1, qA1);
  }
  float sA = sA0 + sA1, qA = qA0 + qA1;
  __builtin_amdgcn_wave_barrier();

  // ---- pass B: channels 32..63 (reuse the same tile) ----
#define STGB(i) *(v4f*)(row + 4 * ((i) - 8)) = a.v##i;
  EACH8HI(STGB)
#undef STGB
  __builtin_amdgcn_wave_barrier();
  float sB0 = 0.f, sB1 = 0.f, qB0 = 0.f, qB1 = 0.f;
#pragma unroll
  for (int p = 0; p < 32; p += 2) {
    float a0 = col[(p + 0) * PADW2_];
    float a1 = col[(p + 1) * PADW2_];
    sB0 += a0; qB0 = fmaf(a0, a0, qB0);
    sB1 += a1; qB1 = fmaf(a1, a1, qB1);
  }
  float sB = sB0 + sB1, qB = qB0 + qB1;

  // merge the two 32-pixel halves: all lanes now hold the 64-pixel wave total
  sA += __shfl_xor(sA, 32, 64);  qA += __shfl_xor(qA, 32, 64);
  sB += __shfl_xor(sB, 32, 64);  qB += __shfl_xor(qB, 32, 64);

  // red layout matches partials: [sum ch0-31 | sum ch32-63 | sq ch0-31 | sq ch32-63]
  if (lane < 32) {
    red[0 * 128 + wid * 32 + c] = sA;
    red[1 * 128 + wid * 32 + c] = sB;
    red[2 * 128 + wid * 32 + c] = qA;
    red[3 * 128 + wid * 32 + c] = qB;
  }
  __syncthreads();
  int tid = threadIdx.x;
  if (tid < 128) {
    int base = (tid >> 5) * 128 + (tid & 31);
    float tot = red[base] + red[base + 32] + red[base + 64] + red[base + 96];
    // partials[blk*128 + c] = sum_c ; partials[blk*128 + 64 + c] = sumsq_c
    partials[(size_t)blockIdx.x * 128 + tid] = tot;
  }
}

// ---------------------------------------------------------------------------
// K2: 64 blocks, one per channel. Block c reduces the sum and sumsq columns
// of partials[3136][128] and writes mean[c], rstd*gamma[c]. The old 1-block
// version pulled 1.6 MB through a single CU (~25 us); 64 blocks make it ~5 us.
// ---------------------------------------------------------------------------
__global__ void k2_finalize(const float* __restrict__ partials, const float* __restrict__ gamma,
                            float* __restrict__ stats) {
  int c = blockIdx.x;      // 0..63
  int t = threadIdx.x;     // 256 threads
  float s = 0.f, q = 0.f;
  for (int i = t; i < NBLK_; i += 256) {
    s += partials[(size_t)i * 128 + c];
    q += partials[(size_t)i * 128 + 64 + c];
  }
  __shared__ float ls[256], lq[256];
  ls[t] = s; lq[t] = q;
  __syncthreads();
#pragma unroll
  for (int off = 128; off > 0; off >>= 1) {
    if (t < off) { ls[t] += ls[t + off]; lq[t] += lq[t + off]; }
    __syncthreads();
  }
  if (t == 0) {
    float mean = ls[0] / NF_;
    float msq  = lq[0] / NF_;
    float var = msq - mean * mean;            // jnp.var (ddof=0)
    stats[c] = mean;
    stats[64 + c] = gamma[c] / sqrtf(var + BN_EPS_);
  }
}

// ---------------------------------------------------------------------------
// K3: conv + clamp + BN affine + clamp + ReLU + real expmap0 (+projx), then
// two 32-channel wave-private LDS transpose passes so the wave's 16 KB output
// region is stored as 16 coalesced instructions (8 x 128B full-sector runs
// per instr, no write amplification) with only 36,864 B of LDS (4 blk/CU).
// tanh via hardware exp: tanh(x) = 1 - 2/(e^{2x}+1) (libm tanhf is branchy);
// cancellation near x=0 only yields ~1e-7 ABSOLUTE output error.
// ---------------------------------------------------------------------------
__global__ void __launch_bounds__(256, 4)
k3_final(const float4* __restrict__ u0p, const float* __restrict__ wgt,
         const float* __restrict__ bias, const float* __restrict__ stats,
         const float* __restrict__ beta, float* __restrict__ out) {
  int pix = blockIdx.x * 256 + threadIdx.x;
  Acc a;
  conv_clamp(u0p, wgt, bias, pix, a);
  const v4f* mean4 = (const v4f*)stats;
  const v4f* rg4   = (const v4f*)(stats + 64);
  const v4f* beta4 = (const v4f*)beta;
  v4f s2 = (v4f)0.0f;
#define BN(i) { a.v##i = (a.v##i - mean4[i]) * rg4[i] + beta4[i]; s2 += a.v##i * a.v##i; }
  EACH16(BN)
#undef BN
  float nv2 = s2.x + s2.y + s2.z + s2.w;
  float nv = sqrtf(nv2);
  float sv = (nv > LCLAMP_) ? (LCLAMP_ / nv) : 1.0f;  // logmap0(expmap0(v)) fused
  // ReLU in tangent space
  v4f z2 = (v4f)0.0f;
#define RELU(i) { v4f r = a.v##i * sv;                                      \
                  r.x = fmaxf(r.x, 0.f); r.y = fmaxf(r.y, 0.f);             \
                  r.z = fmaxf(r.z, 0.f); r.w = fmaxf(r.w, 0.f);             \
                  a.v##i = r; z2 += r * r; }
  EACH16(RELU)
#undef RELU
  float nw2 = z2.x + z2.y + z2.z + z2.w;
  // final expmap0 + projx (the only real tanh)
  float nw = fmaxf(sqrtf(nw2), MINN_);
  float e2 = __expf(2.0f * nw);
  float th = 1.0f - __fdividef(2.0f, e2 + 1.0f);
  float se = __fdividef(th, nw);
  float clip = fminf(1.0f, MAXNORM_ / fmaxf(th, MINN_));
  float fs = se * clip;

  // ---- coalescing transpose: regs -> wave-private LDS half-tile -> global ----
  __shared__ __align__(16) float stg[4 * 64 * PADW2_];  // 36,864 B -> 4 blk/CU
  int lane = threadIdx.x & 63, wid = threadIdx.x >> 6;
  float* row = stg + (size_t)(wid * 64 + lane) * PADW2_;
  int pr8 = lane >> 3, qi = lane & 7;
  const float* rb = stg + (size_t)wid * 64 * PADW2_ + pr8 * PADW2_ + qi * 4;
  v4f* outw = (v4f*)out + ((size_t)blockIdx.x * 256 + wid * 64) * 16;

  // ---- pass A: channels 0..31 ----
#define STGA(i) *(v4f*)(row + 4 * (i)) = a.v##i * fs;
  EACH8LO(STGA)
#undef STGA
  __builtin_amdgcn_wave_barrier();
#pragma unroll
  for (int j = 0; j < 8; j++) {
    // instr j: pixels j*8..j*8+7, ch-quads 0..7 -> 8 contiguous 128B runs
    v4f v = *(const v4f*)(rb + j * 8 * PADW2_);
    __builtin_nontemporal_store(v, outw + (j * 8 + pr8) * 16 + qi);
  }
  __builtin_amdgcn_wave_barrier();

  // ---- pass B: channels 32..63 ----
#define STGB(i) *(v4f*)(row + 4 * ((i) - 8)) = a.v##i * fs;
  EACH8HI(STGB)
#undef STGB
  __builtin_amdgcn_wave_barrier();
#pragma unroll
  for (int j = 0; j < 8; j++) {
    v4f v = *(const v4f*)(rb + j * 8 * PADW2_);
    __builtin_nontemporal_store(v, outw + (j * 8 + pr8) * 16 + 8 + qi);
  }
}

// ---------------------------------------------------------------------------
extern "C" void kernel_launch(void* const* d_in, const int* in_sizes, int n_in,
                              void* d_out, int out_size, void* d_ws, size_t ws_size,
                              hipStream_t stream) {
  const float* x     = (const float*)d_in[0];  // [16,3,224,224]
  const float* wgt   = (const float*)d_in[1];  // [3,3,3,64] HWIO
  const float* bias  = (const float*)d_in[2];  // [64]
  const float* gamma = (const float*)d_in[3];  // [64]
  const float* beta  = (const float*)d_in[4];  // [64]
  float* out = (float*)d_out;                  // [16,224,224,64]

  char* ws = (char*)d_ws;
  float4* u0p      = (float4*)ws;                                           // 13,075,456 B
  float*  partials = (float*)(ws + (size_t)NPAD_ * 16);                     //  1,605,632 B
  float*  stats    = (float*)(ws + (size_t)NPAD_ * 16 + (size_t)NBLK_ * 128 * 4); // 512 B

  hipLaunchKernelGGL(k0_transform, dim3((NPAD_ + 255) / 256), dim3(256), 0, stream, x, u0p);
  hipLaunchKernelGGL(k1_stats,     dim3(NBLK_),               dim3(256), 0, stream, u0p, wgt, bias, partials);
  hipLaunchKernelGGL(k2_finalize,  dim3(64),                  dim3(256), 0, stream, partials, gamma, stats);
  hipLaunchKernelGGL(k3_final,     dim3(NBLK_),               dim3(256), 0, stream, u0p, wgt, bias, stats, beta, out);
}